// Round 1
// baseline (312.472 us; speedup 1.0000x reference)
//
#include <hip/hip_runtime.h>
#include <hip/hip_bf16.h>

// Problem constants: B=4, N=2048, F=128, D=64, H=4
constexpr int CB = 4, CN = 2048, CF = 128, CD = 64, CH = 4;
constexpr float FNEG = -1000000000.0f;
constexpr int ITILE = 32;   // i-rows per block in attention kernel
constexpr int CHUNK = 16;   // j-chunk per weight/FMA phase
constexpr int WPAD  = 36;   // 32 rows + 4 pad words -> head stride = 36 words = 4 banks

// ---------------------------------------------------------------------------
// Kernel 0: pack adjacency int32 -> bitmask (2048x2048 bits = 512 KB)
// ---------------------------------------------------------------------------
__global__ __launch_bounds__(256) void pack_mask_k(const int* __restrict__ A,
                                                   unsigned long long* __restrict__ mask) {
    int gid = blockIdx.x * 256 + threadIdx.x;
    unsigned long long mk = __ballot(A[gid] > 0);
    if ((threadIdx.x & 63) == 0) mask[gid >> 6] = mk;
}

// ---------------------------------------------------------------------------
// Kernel 1: h[h,b,n,d] = sum_f X[b,n,f]*W[h,f,d];  s[h,b,n] = sum_d h*a[h,d]
// block = (h, b, 32-row tile), 256 threads: lane d = t&63, row-group g = t>>6
// ---------------------------------------------------------------------------
__global__ __launch_bounds__(256) void proj_k(const float* __restrict__ X,
                                              const float* __restrict__ W,
                                              const float* __restrict__ AK,
                                              float* __restrict__ hout,
                                              float* __restrict__ sout) {
    __shared__ float klds[CF * CD];   // 32 KB  [f][d]
    __shared__ float xlds[32 * CF];   // 16 KB  [r][f]
    int blk = blockIdx.x;
    int ntile = blk & 63;
    int b = (blk >> 6) & 3;
    int h = blk >> 8;
    int n0 = ntile * 32;
    int t = threadIdx.x;

    for (int idx = t; idx < CF * CD; idx += 256) klds[idx] = W[h * CF * CD + idx];
    for (int idx = t; idx < 32 * CF; idx += 256)
        xlds[idx] = X[((size_t)b * CN + n0 + (idx >> 7)) * CF + (idx & 127)];
    __syncthreads();

    int d = t & 63, g = t >> 6;
    float acc[8];
#pragma unroll
    for (int r = 0; r < 8; ++r) acc[r] = 0.f;

    for (int f = 0; f < CF; f += 4) {
        float k0 = klds[(f + 0) * CD + d];
        float k1 = klds[(f + 1) * CD + d];
        float k2 = klds[(f + 2) * CD + d];
        float k3 = klds[(f + 3) * CD + d];
#pragma unroll
        for (int r = 0; r < 8; ++r) {
            float4 xv = *reinterpret_cast<const float4*>(&xlds[(g * 8 + r) * CF + f]);
            acc[r] += xv.x * k0 + xv.y * k1 + xv.z * k2 + xv.w * k3;
        }
    }

    float ak = AK[h * CD + d];
#pragma unroll
    for (int r = 0; r < 8; ++r) {
        int n = n0 + g * 8 + r;
        hout[((size_t)(h * CB + b) * CN + n) * CD + d] = acc[r];
        float sv = acc[r] * ak;
#pragma unroll
        for (int off = 32; off >= 1; off >>= 1) sv += __shfl_xor(sv, off, 64);
        if (d == 0) sout[(size_t)(h * CB + b) * CN + n] = sv;
    }
}

// ---------------------------------------------------------------------------
// Kernel 2: fused masked-softmax + PV + head-mean + leaky_relu
// block = (b, 32-row i-tile); grid = 4*64 = 256 blocks; 256 threads.
// Weight phase identity: (hw = t>>6, i_w = t&31, half = (t>>5)&1)
// FMA phase identity:    (g = t>>6, hq = (t>>4)&3, dblk = t&15), acc[8 rows][4 d]
// ---------------------------------------------------------------------------
__global__ __launch_bounds__(256) void attn_k(const float* __restrict__ hin,
                                              const float* __restrict__ sin,
                                              const unsigned int* __restrict__ mask32,
                                              float* __restrict__ out) {
    __shared__ float s_lds[CH * CN];               // 32 KB: s rows for 4 heads
    __shared__ unsigned int mask_lds[ITILE * 65];  // 8.3 KB (65: bank-spread pad)
    __shared__ float w_lds[CHUNK * CH * WPAD];     // 9.2 KB
    __shared__ float lpart[CH * ITILE * 2];
    __shared__ float smax_lds[CH];

    int blk = blockIdx.x;
    int b = blk >> 6;
    int i0 = (blk & 63) * ITILE;
    int t = threadIdx.x;

    // stage s (all 4 heads) and this tile's mask rows
    for (int idx = t; idx < CH * CN; idx += 256) {
        int hh = idx >> 11, j = idx & (CN - 1);
        s_lds[idx] = sin[(size_t)(hh * CB + b) * CN + j];
    }
    for (int idx = t; idx < ITILE * 64; idx += 256) {
        int il = idx >> 6, w = idx & 63;
        mask_lds[il * 65 + w] = mask32[(size_t)(i0 + il) * 64 + w];
    }
    __syncthreads();

    // global per-head max of s (upper bound for softmax stabilizer)
    {
        int wv = t >> 6, lane = t & 63;
        float M = FNEG;
        for (int jj = lane; jj < CN; jj += 64) M = fmaxf(M, s_lds[wv * CN + jj]);
#pragma unroll
        for (int off = 32; off >= 1; off >>= 1) M = fmaxf(M, __shfl_xor(M, off, 64));
        if (lane == 0) smax_lds[wv] = M;
    }
    __syncthreads();

    // weight-phase identity
    int hw = t >> 6;
    int i_w = t & 31;
    int half = (t >> 5) & 1;
    float si_reg = s_lds[hw * CN + i0 + i_w];
    float m_reg = fmaxf(si_reg + smax_lds[hw], 0.f);  // >= every e_ij of this row
    float lacc = 0.f;

    // FMA-phase identity
    int g = t >> 6;
    int hq = (t >> 4) & 3;
    int dblk = t & 15;
    const float4* hrow =
        reinterpret_cast<const float4*>(hin) + (size_t)(hq * CB + b) * CN * (CD / 4);

    float4 acc4[8];
#pragma unroll
    for (int r = 0; r < 8; ++r) acc4[r] = make_float4(0.f, 0.f, 0.f, 0.f);

    for (int j0 = 0; j0 < CN; j0 += CHUNK) {
        // ---- weight phase: w = A_ij ? exp(relu(si+sj) - m) : 0 ----
        unsigned int word = mask_lds[i_w * 65 + (j0 >> 5)];
        int bitbase = (j0 & 31) + half * 8;
#pragma unroll
        for (int k = 0; k < 8; ++k) {
            int j = j0 + half * 8 + k;
            float sj = s_lds[hw * CN + j];
            float e = fmaxf(si_reg + sj, 0.f);
            float ex = __expf(e - m_reg);
            float wvv = ((word >> (bitbase + k)) & 1u) ? ex : 0.f;
            lacc += wvv;
            w_lds[((half * 8 + k) * CH + hw) * WPAD + i_w] = wvv;
        }
        __syncthreads();

        // ---- FMA phase: acc[r][c] += w[r] * h[j][c] ----
#pragma unroll 4
        for (int jc = 0; jc < CHUNK; ++jc) {
            int j = j0 + jc;
            float4 hv = hrow[j * (CD / 4) + dblk];
            const float* wp = &w_lds[(jc * CH + hq) * WPAD + g * 8];
            float4 wa = *reinterpret_cast<const float4*>(wp);
            float4 wb = *reinterpret_cast<const float4*>(wp + 4);
            float wr[8] = {wa.x, wa.y, wa.z, wa.w, wb.x, wb.y, wb.z, wb.w};
#pragma unroll
            for (int r = 0; r < 8; ++r) {
                acc4[r].x += wr[r] * hv.x;
                acc4[r].y += wr[r] * hv.y;
                acc4[r].z += wr[r] * hv.z;
                acc4[r].w += wr[r] * hv.w;
            }
        }
        __syncthreads();
    }

    // combine softmax denominators
    lpart[(hw * ITILE + i_w) * 2 + half] = lacc;
    __syncthreads();

    float4* outp = reinterpret_cast<float4*>(out) + (size_t)b * CN * (CD / 4);
#pragma unroll
    for (int r = 0; r < 8; ++r) {
        int i = g * 8 + r;
        float l = lpart[(hq * ITILE + i) * 2] + lpart[(hq * ITILE + i) * 2 + 1] + 1e-35f;
        float rl = 1.0f / l;
        float4 v = acc4[r];
        v.x *= rl; v.y *= rl; v.z *= rl; v.w *= rl;
        // mean over heads: heads sit 16 lanes apart within the wave
        v.x += __shfl_xor(v.x, 16, 64); v.x += __shfl_xor(v.x, 32, 64);
        v.y += __shfl_xor(v.y, 16, 64); v.y += __shfl_xor(v.y, 32, 64);
        v.z += __shfl_xor(v.z, 16, 64); v.z += __shfl_xor(v.z, 32, 64);
        v.w += __shfl_xor(v.w, 16, 64); v.w += __shfl_xor(v.w, 32, 64);
        if (hq == 0) {
            float4 o;
            float m0 = v.x * 0.25f; o.x = m0 > 0.f ? m0 : 0.2f * m0;
            float m1 = v.y * 0.25f; o.y = m1 > 0.f ? m1 : 0.2f * m1;
            float m2 = v.z * 0.25f; o.z = m2 > 0.f ? m2 : 0.2f * m2;
            float m3 = v.w * 0.25f; o.w = m3 > 0.f ? m3 : 0.2f * m3;
            outp[(size_t)(i0 + i) * (CD / 4) + dblk] = o;
        }
    }
}

// ---------------------------------------------------------------------------
extern "C" void kernel_launch(void* const* d_in, const int* in_sizes, int n_in,
                              void* d_out, int out_size, void* d_ws, size_t ws_size,
                              hipStream_t stream) {
    const float* X  = (const float*)d_in[0];   // [B,N,F]
    const int*   A  = (const int*)d_in[1];     // [N,N]
    const float* W  = (const float*)d_in[2];   // [H,F,D]
    const float* AK = (const float*)d_in[3];   // [H,D]
    float* out = (float*)d_out;                // [B,N,D]

    // workspace layout
    float* h_ws = (float*)d_ws;                           // H*B*N*D f32 = 8 MB
    float* s_ws = h_ws + (size_t)CH * CB * CN * CD;       // H*B*N f32 = 512 KB? (128K floats)
    unsigned long long* mask_ws =
        (unsigned long long*)(s_ws + (size_t)CH * CB * CN);  // N*N/64 u64 = 512 KB

    pack_mask_k<<<CN * CN / 256, 256, 0, stream>>>(A, mask_ws);
    proj_k<<<CH * CB * (CN / 32), 256, 0, stream>>>(X, W, AK, h_ws, s_ws);
    attn_k<<<CB * (CN / ITILE), 256, 0, stream>>>(h_ws, s_ws,
                                                  (const unsigned int*)mask_ws, out);
}

// Round 2
// 125.113 us; speedup vs baseline: 2.4975x; 2.4975x over previous
//
#include <hip/hip_runtime.h>
#include <hip/hip_bf16.h>

typedef __attribute__((ext_vector_type(8))) short short8;
typedef __attribute__((ext_vector_type(4))) float f32x4;
typedef unsigned short u16;
typedef unsigned int u32;

constexpr int CB = 4, CN = 2048, CF = 128, CD = 64, CH = 4;

// ---------------------------------------------------------------------------
// Kernel 0: pack adjacency int32 -> bitmask words (u32, [row][64 words])
// ---------------------------------------------------------------------------
__global__ __launch_bounds__(256) void pack_mask_k(const int* __restrict__ A,
                                                   u32* __restrict__ mask) {
    int gid = blockIdx.x * 256 + threadIdx.x;
    unsigned long long mk = __ballot(A[gid] > 0);
    if ((threadIdx.x & 63) == 0) {
        mask[gid >> 5] = (u32)mk;
        mask[(gid >> 5) + 1] = (u32)(mk >> 32);
    }
}

// ---------------------------------------------------------------------------
// Kernel 1: projection. Emits hT bf16 hi/lo [h][b][p][d][j] and s f32 [h][b][n].
// block = (h, b, 32-row tile), 256 threads.
// ---------------------------------------------------------------------------
__global__ __launch_bounds__(256) void proj_k(const float* __restrict__ X,
                                              const float* __restrict__ W,
                                              const float* __restrict__ AK,
                                              u16* __restrict__ hT,
                                              float* __restrict__ sout) {
    __shared__ float klds[CF * CD];   // 32 KB [f][d]
    __shared__ float xlds[32 * CF];   // 16 KB [r][f]
    __shared__ float tr[CD][33];      // 8.4 KB transpose staging
    int blk = blockIdx.x;
    int ntile = blk & 63;
    int b = (blk >> 6) & 3;
    int h = blk >> 8;
    int n0 = ntile * 32;
    int t = threadIdx.x;

    for (int idx = t; idx < CF * CD; idx += 256) klds[idx] = W[h * CF * CD + idx];
    for (int idx = t; idx < 32 * CF; idx += 256)
        xlds[idx] = X[((size_t)b * CN + n0 + (idx >> 7)) * CF + (idx & 127)];
    __syncthreads();

    int d = t & 63, g = t >> 6;
    float acc[8];
#pragma unroll
    for (int r = 0; r < 8; ++r) acc[r] = 0.f;

    for (int f = 0; f < CF; f += 4) {
        float k0 = klds[(f + 0) * CD + d];
        float k1 = klds[(f + 1) * CD + d];
        float k2 = klds[(f + 2) * CD + d];
        float k3 = klds[(f + 3) * CD + d];
#pragma unroll
        for (int r = 0; r < 8; ++r) {
            float4 xv = *reinterpret_cast<const float4*>(&xlds[(g * 8 + r) * CF + f]);
            acc[r] += xv.x * k0 + xv.y * k1 + xv.z * k2 + xv.w * k3;
        }
    }

    float ak = AK[h * CD + d];
#pragma unroll
    for (int r = 0; r < 8; ++r) {
        float sv = acc[r] * ak;
#pragma unroll
        for (int off = 32; off >= 1; off >>= 1) sv += __shfl_xor(sv, off, 64);
        if (d == 0) sout[(size_t)(h * CB + b) * CN + n0 + g * 8 + r] = sv;
        tr[d][g * 8 + r] = acc[r];
    }
    __syncthreads();

    // bf16 hi/lo split, stored d-major for B-fragment loads
    int d_o = t >> 2, q = t & 3;
    short8 vhi, vlo;
#pragma unroll
    for (int k = 0; k < 8; ++k) {
        float v = tr[d_o][q * 8 + k];
        __hip_bfloat16 bh = __float2bfloat16(v);
        vhi[k] = (short)*reinterpret_cast<u16*>(&bh);
        float res = v - __bfloat162float(bh);
        __hip_bfloat16 bl = __float2bfloat16(res);
        vlo[k] = (short)*reinterpret_cast<u16*>(&bl);
    }
    size_t basehi = ((size_t)((h * CB + b) * 2 + 0) * CD + d_o) * CN + n0 + q * 8;
    size_t baselo = ((size_t)((h * CB + b) * 2 + 1) * CD + d_o) * CN + n0 + q * 8;
    *reinterpret_cast<short8*>(hT + basehi) = vhi;
    *reinterpret_cast<short8*>(hT + baselo) = vlo;
}

// ---------------------------------------------------------------------------
// Kernel 2: global max of s (softmax stabilizer upper bound), one block
// ---------------------------------------------------------------------------
__global__ __launch_bounds__(256) void smax_k(const float* __restrict__ s,
                                              float* __restrict__ smax) {
    __shared__ float red[4];
    int t = threadIdx.x;
    float M = -1e30f;
    for (int i = t; i < CH * CB * CN; i += 256) M = fmaxf(M, s[i]);
#pragma unroll
    for (int off = 32; off >= 1; off >>= 1) M = fmaxf(M, __shfl_xor(M, off, 64));
    if ((t & 63) == 0) red[t >> 6] = M;
    __syncthreads();
    if (t == 0) smax[0] = fmaxf(fmaxf(red[0], red[1]), fmaxf(red[2], red[3]));
}

// ---------------------------------------------------------------------------
// Kernel 3: MFMA flash PV. block = (b, 32-row i-tile, k-slice of 1024),
// grid = 4*64*2 = 512, 256 threads = 4 waves (wave = head).
// Per wave: 2 i-subtiles x 4 d-tiles, K-loop 32 steps of 32 j.
// A-frag (weights) computed in-register; B-frags (h hi/lo) from global.
// 3-MFMA compensated product: hi*hi + hi*lo + lo*hi.
// ---------------------------------------------------------------------------
__global__ __launch_bounds__(256, 2) void attn_k(const u16* __restrict__ hT,
                                                 const float* __restrict__ s_ws,
                                                 const float* __restrict__ smax_ws,
                                                 const u32* __restrict__ mask32,
                                                 float* __restrict__ partC,
                                                 float* __restrict__ partL) {
    __shared__ float s_sl[CH][1024];   // 16 KB: slice of s, 4 heads
    __shared__ u32 m_lds[32][33];      // 4.2 KB: mask words (pad 33 vs bank clash)

    int blk = blockIdx.x;
    int sl = blk & 1;
    int it = (blk >> 1) & 63;
    int b = blk >> 7;
    int t = threadIdx.x, l = t & 63, hq = t >> 6;
    int j_base = sl * 1024;

    for (int idx = t; idx < CH * 1024; idx += 256) {
        int hh = idx >> 10, j = idx & 1023;
        s_sl[hh][j] = s_ws[(size_t)(hh * CB + b) * CN + j_base + j];
    }
    for (int idx = t; idx < 32 * 32; idx += 256) {
        int r = idx >> 5, w = idx & 31;
        m_lds[r][w] = mask32[(size_t)(it * 32 + r) * 64 + sl * 32 + w];
    }
    __syncthreads();

    float smax = smax_ws[0];
    int row_l = l & 15;   // A row / B,D col within 16
    int jg = l >> 4;      // k-group
    float si0 = s_ws[(size_t)(hq * CB + b) * CN + it * 32 + row_l];
    float si1 = s_ws[(size_t)(hq * CB + b) * CN + it * 32 + 16 + row_l];
    float m0 = fmaxf(si0 + smax, 0.f);
    float m1 = fmaxf(si1 + smax, 0.f);
    float ls0 = 0.f, ls1 = 0.f;

    f32x4 c[2][4];
    f32x4 zero = {0.f, 0.f, 0.f, 0.f};
#pragma unroll
    for (int i = 0; i < 2; ++i)
#pragma unroll
        for (int dd = 0; dd < 4; ++dd) c[i][dd] = zero;

    // per-lane B pointers: hT[(hq,b)][p][d = dt*16+row_l][j_base + jg*8 + ...]
    const u16* bp[4][2];
#pragma unroll
    for (int dt = 0; dt < 4; ++dt)
#pragma unroll
        for (int p = 0; p < 2; ++p)
            bp[dt][p] = hT + ((size_t)((hq * CB + b) * 2 + p) * CD + dt * 16 + row_l) * CN +
                        j_base + jg * 8;

#pragma unroll 2
    for (int kk = 0; kk < 32; ++kk) {
        int j0 = kk * 32;
        // B fragments (8 x 16B contiguous loads, L2-resident)
        short8 bf[4][2];
#pragma unroll
        for (int dt = 0; dt < 4; ++dt)
#pragma unroll
            for (int p = 0; p < 2; ++p)
                bf[dt][p] = *reinterpret_cast<const short8*>(bp[dt][p] + j0);

        // s_j for this lane's 8 k's
        int jl = j0 + jg * 8;
        f32x4 sj0 = *reinterpret_cast<const f32x4*>(&s_sl[hq][jl]);
        f32x4 sj1 = *reinterpret_cast<const f32x4*>(&s_sl[hq][jl + 4]);

        u32 byte0 = m_lds[row_l][kk] >> (jg * 8);
        u32 byte1 = m_lds[16 + row_l][kk] >> (jg * 8);

        float p0[8], p1[8];
#pragma unroll
        for (int e = 0; e < 8; ++e) {
            float sjv = (e < 4) ? sj0[e] : sj1[e - 4];
            float a0 = fmaxf(si0 + sjv, 0.f) - m0;
            float a1 = fmaxf(si1 + sjv, 0.f) - m1;
            float e0 = ((byte0 >> e) & 1u) ? __expf(a0) : 0.f;
            float e1 = ((byte1 >> e) & 1u) ? __expf(a1) : 0.f;
            p0[e] = e0; p1[e] = e1;
            ls0 += e0; ls1 += e1;
        }

        // pack weights to bf16 hi + residual lo (A fragments, in-register)
        short8 ah0, al0, ah1, al1;
#pragma unroll
        for (int e = 0; e < 8; ++e) {
            __hip_bfloat16 h0 = __float2bfloat16(p0[e]);
            ah0[e] = (short)*reinterpret_cast<u16*>(&h0);
            __hip_bfloat16 l0v = __float2bfloat16(p0[e] - __bfloat162float(h0));
            al0[e] = (short)*reinterpret_cast<u16*>(&l0v);
            __hip_bfloat16 h1 = __float2bfloat16(p1[e]);
            ah1[e] = (short)*reinterpret_cast<u16*>(&h1);
            __hip_bfloat16 l1v = __float2bfloat16(p1[e] - __bfloat162float(h1));
            al1[e] = (short)*reinterpret_cast<u16*>(&l1v);
        }

#pragma unroll
        for (int dt = 0; dt < 4; ++dt) {
            c[0][dt] = __builtin_amdgcn_mfma_f32_16x16x32_bf16(ah0, bf[dt][0], c[0][dt], 0, 0, 0);
            c[0][dt] = __builtin_amdgcn_mfma_f32_16x16x32_bf16(ah0, bf[dt][1], c[0][dt], 0, 0, 0);
            c[0][dt] = __builtin_amdgcn_mfma_f32_16x16x32_bf16(al0, bf[dt][0], c[0][dt], 0, 0, 0);
            c[1][dt] = __builtin_amdgcn_mfma_f32_16x16x32_bf16(ah1, bf[dt][0], c[1][dt], 0, 0, 0);
            c[1][dt] = __builtin_amdgcn_mfma_f32_16x16x32_bf16(ah1, bf[dt][1], c[1][dt], 0, 0, 0);
            c[1][dt] = __builtin_amdgcn_mfma_f32_16x16x32_bf16(al1, bf[dt][0], c[1][dt], 0, 0, 0);
        }
    }

    // denominator: reduce partial sums across the 4 k-groups (same row lanes)
    ls0 += __shfl_xor(ls0, 16, 64); ls0 += __shfl_xor(ls0, 32, 64);
    ls1 += __shfl_xor(ls1, 16, 64); ls1 += __shfl_xor(ls1, 32, 64);

    size_t base = ((((size_t)b * 64 + it) * 2 + sl) * CH + hq);
    if (jg == 0) {
        partL[base * 32 + row_l] = ls0;
        partL[base * 32 + 16 + row_l] = ls1;
    }

    // C/D layout (m89-verified): col = lane&15, row = (lane>>4)*4 + reg
#pragma unroll
    for (int isub = 0; isub < 2; ++isub)
#pragma unroll
        for (int dt = 0; dt < 4; ++dt)
#pragma unroll
            for (int r = 0; r < 4; ++r) {
                int row = isub * 16 + jg * 4 + r;
                int dcol = dt * 16 + row_l;
                partC[(base * 32 + row) * 64 + dcol] = c[isub][dt][r];
            }
}

// ---------------------------------------------------------------------------
// Kernel 4: combine k-slices, divide by l, mean over heads, leaky relu
// ---------------------------------------------------------------------------
__global__ __launch_bounds__(256) void combine_k(const float* __restrict__ partC,
                                                 const float* __restrict__ partL,
                                                 float* __restrict__ out) {
    int idx = blockIdx.x * 256 + threadIdx.x;   // [b][i][d] flat, 512K
    int d = idx & 63;
    int i = (idx >> 6) & 2047;
    int b = idx >> 17;
    int it = i >> 5, il = i & 31;
    float acc = 0.f;
#pragma unroll
    for (int h = 0; h < CH; ++h) {
        size_t b0 = (((size_t)b * 64 + it) * 2 + 0) * CH + h;
        size_t b1 = (((size_t)b * 64 + it) * 2 + 1) * CH + h;
        float num = partC[(b0 * 32 + il) * 64 + d] + partC[(b1 * 32 + il) * 64 + d];
        float den = partL[b0 * 32 + il] + partL[b1 * 32 + il];
        acc += num / fmaxf(den, 1e-30f);
    }
    float o = acc * 0.25f;
    out[idx] = o > 0.f ? o : 0.2f * o;
}

// ---------------------------------------------------------------------------
extern "C" void kernel_launch(void* const* d_in, const int* in_sizes, int n_in,
                              void* d_out, int out_size, void* d_ws, size_t ws_size,
                              hipStream_t stream) {
    const float* X  = (const float*)d_in[0];   // [B,N,F]
    const int*   A  = (const int*)d_in[1];     // [N,N]
    const float* W  = (const float*)d_in[2];   // [H,F,D]
    const float* AK = (const float*)d_in[3];   // [H,D]
    float* out = (float*)d_out;                // [B,N,D]

    char* w = (char*)d_ws;
    float* s_ws = (float*)w;        w += 131072;    // 16*2048 f32
    float* smax_ws = (float*)w;     w += 256;
    u32* mask_ws = (u32*)w;         w += 524288;    // 2048*64 u32
    u16* hT = (u16*)w;              w += 8388608;   // 4*4*2*64*2048 bf16
    float* partC = (float*)w;       w += 16777216;  // 4*64*2*4*32*64 f32
    float* partL = (float*)w;       w += 262144;    // 4*64*2*4*32 f32 (padded)

    pack_mask_k<<<CN * CN / 256, 256, 0, stream>>>(A, mask_ws);
    proj_k<<<CH * CB * (CN / 32), 256, 0, stream>>>(X, W, AK, hT, s_ws);
    smax_k<<<1, 256, 0, stream>>>(s_ws, smax_ws);
    attn_k<<<CB * 64 * 2, 256, 0, stream>>>(hT, s_ws, smax_ws, mask_ws, partC, partL);
    combine_k<<<CB * CN * CD / 256, 256, 0, stream>>>(partC, partL, out);
}

// Round 3
// 103.774 us; speedup vs baseline: 3.0111x; 1.2056x over previous
//
#include <hip/hip_runtime.h>
#include <hip/hip_bf16.h>

typedef __attribute__((ext_vector_type(8))) short short8;
typedef __attribute__((ext_vector_type(4))) float f32x4;
typedef unsigned short u16;
typedef unsigned int u32;

constexpr int CB = 4, CN = 2048, CF = 128, CD = 64, CH = 4;
constexpr int ITILE = 64;   // i-rows per attn block (4 MFMA subtiles)
constexpr int NSL = 4;      // k-slices; slice length = 512

__device__ inline u32 fmap(float f) {
    u32 b = __float_as_uint(f);
    return b ^ ((u32)(((int)b) >> 31) | 0x80000000u);
}
__device__ inline float funmap(u32 u) {
    u32 b = (u & 0x80000000u) ? (u ^ 0x80000000u) : ~u;
    return __uint_as_float(b);
}

// ---------------------------------------------------------------------------
// Kernel 0: pack adjacency -> bitmask; also init smax accumulators (runs
// before proj_k in stream order every launch -> deterministic).
// ---------------------------------------------------------------------------
__global__ __launch_bounds__(256) void pack_mask_k(const int* __restrict__ A,
                                                   u32* __restrict__ mask,
                                                   u32* __restrict__ smax_u) {
    int gid = blockIdx.x * 256 + threadIdx.x;
    if (blockIdx.x == 0 && threadIdx.x < CH * CB) smax_u[threadIdx.x] = 0u;  // ~ -inf
    unsigned long long mk = __ballot(A[gid] > 0);
    if ((threadIdx.x & 63) == 0) {
        mask[gid >> 5] = (u32)mk;
        mask[(gid >> 5) + 1] = (u32)(mk >> 32);
    }
}

// ---------------------------------------------------------------------------
// Kernel 1: projection. Emits hT bf16 [h][b][d][j], s f32, E=exp(s) f32,
// and per-(h,b) smax via mapped atomicMax.
// block = (h, b, 32-row tile), 256 threads.
// ---------------------------------------------------------------------------
__global__ __launch_bounds__(256) void proj_k(const float* __restrict__ X,
                                              const float* __restrict__ W,
                                              const float* __restrict__ AK,
                                              u16* __restrict__ hT,
                                              float* __restrict__ sout,
                                              float* __restrict__ eout,
                                              u32* __restrict__ smax_u) {
    __shared__ float klds[CF * CD];   // 32 KB [f][d]
    __shared__ float xlds[32 * CF];   // 16 KB [r][f]
    __shared__ float tr[CD][33];      // transpose staging
    int blk = blockIdx.x;
    int ntile = blk & 63;
    int b = (blk >> 6) & 3;
    int h = blk >> 8;
    int n0 = ntile * 32;
    int t = threadIdx.x;

    for (int idx = t; idx < CF * CD; idx += 256) klds[idx] = W[h * CF * CD + idx];
    for (int idx = t; idx < 32 * CF; idx += 256)
        xlds[idx] = X[((size_t)b * CN + n0 + (idx >> 7)) * CF + (idx & 127)];
    __syncthreads();

    int d = t & 63, g = t >> 6;
    float acc[8];
#pragma unroll
    for (int r = 0; r < 8; ++r) acc[r] = 0.f;

    for (int f = 0; f < CF; f += 4) {
        float k0 = klds[(f + 0) * CD + d];
        float k1 = klds[(f + 1) * CD + d];
        float k2 = klds[(f + 2) * CD + d];
        float k3 = klds[(f + 3) * CD + d];
#pragma unroll
        for (int r = 0; r < 8; ++r) {
            float4 xv = *reinterpret_cast<const float4*>(&xlds[(g * 8 + r) * CF + f]);
            acc[r] += xv.x * k0 + xv.y * k1 + xv.z * k2 + xv.w * k3;
        }
    }

    float ak = AK[h * CD + d];
    float mx = -1e30f;
#pragma unroll
    for (int r = 0; r < 8; ++r) {
        float sv = acc[r] * ak;
#pragma unroll
        for (int off = 32; off >= 1; off >>= 1) sv += __shfl_xor(sv, off, 64);
        mx = fmaxf(mx, sv);
        if (d == 0) {
            size_t si = (size_t)(h * CB + b) * CN + n0 + g * 8 + r;
            sout[si] = sv;
            eout[si] = __expf(sv);
        }
        tr[d][g * 8 + r] = acc[r];
    }
    if ((t & 63) == 0) atomicMax(&smax_u[h * CB + b], fmap(mx));
    __syncthreads();

    // bf16 (hi only), stored d-major for B-fragment loads
    int d_o = t >> 2, q = t & 3;
    short8 vhi;
#pragma unroll
    for (int k = 0; k < 8; ++k) {
        __hip_bfloat16 bh = __float2bfloat16(tr[d_o][q * 8 + k]);
        vhi[k] = (short)*reinterpret_cast<u16*>(&bh);
    }
    *reinterpret_cast<short8*>(hT + ((size_t)((h * CB + b) * CD + d_o)) * CN + n0 + q * 8) = vhi;
}

// ---------------------------------------------------------------------------
// Kernel 2: MFMA flash PV. block = (b, 64-row i-tile, k-slice of 512),
// grid = 4*32*4 = 512, 256 threads = 4 waves (wave = head).
// Weight w = mask ? max(Ei*Ej, Ci) : 0   (no transcendentals in loop).
// Denominator = ones-column MFMA of the SAME bf16-rounded A-frag
// -> numerator/denominator exactly consistent.
// ---------------------------------------------------------------------------
__global__ __launch_bounds__(256, 2) void attn_k(const u16* __restrict__ hT,
                                                 const float* __restrict__ s_ws,
                                                 const float* __restrict__ e_ws,
                                                 const u32* __restrict__ smax_u,
                                                 const u32* __restrict__ mask32,
                                                 float* __restrict__ partC,
                                                 float* __restrict__ partL) {
    __shared__ alignas(16) float e_sl[CH][512];  // 8 KB: E_j slice, 4 heads
    __shared__ u32 m_lds[ITILE][17];             // 4.4 KB mask words (pad)

    int blk = blockIdx.x;
    int sl = blk & 3;
    int it = (blk >> 2) & 31;
    int b = blk >> 7;
    int t = threadIdx.x, l = t & 63, hq = t >> 6;
    int j_base = sl * 512;

    for (int idx = t; idx < CH * 512; idx += 256) {
        int hh = idx >> 9, j = idx & 511;
        e_sl[hh][j] = e_ws[(size_t)(hh * CB + b) * CN + j_base + j];
    }
    for (int idx = t; idx < ITILE * 16; idx += 256) {
        int r = idx >> 4, w = idx & 15;
        m_lds[r][w] = mask32[(size_t)(it * ITILE + r) * 64 + sl * 16 + w];
    }
    __syncthreads();

    int row_l = l & 15;   // A row / D col within 16
    int jg = l >> 4;      // k-group
    float smax = funmap(smax_u[hq * CB + b]);

    float Ei[4], Ci[4];
#pragma unroll
    for (int is = 0; is < 4; ++is) {
        float si = s_ws[(size_t)(hq * CB + b) * CN + it * ITILE + is * 16 + row_l];
        float m = fmaxf(si + smax, 0.f);
        Ei[is] = __expf(si - m);
        Ci[is] = __expf(-m);
    }

    f32x4 c[4][4], cl[4];
    f32x4 zero = {0.f, 0.f, 0.f, 0.f};
#pragma unroll
    for (int is = 0; is < 4; ++is) {
        cl[is] = zero;
#pragma unroll
        for (int dt = 0; dt < 4; ++dt) c[is][dt] = zero;
    }

    short8 ones;
#pragma unroll
    for (int e = 0; e < 8; ++e) ones[e] = (short)0x3F80;  // bf16 1.0

    const u16* bp[4];
#pragma unroll
    for (int dt = 0; dt < 4; ++dt)
        bp[dt] = hT + ((size_t)((hq * CB + b) * CD + dt * 16 + row_l)) * CN + j_base + jg * 8;

#pragma unroll 2
    for (int kk = 0; kk < 16; ++kk) {
        int j0 = kk * 32;
        short8 bf[4];
#pragma unroll
        for (int dt = 0; dt < 4; ++dt)
            bf[dt] = *reinterpret_cast<const short8*>(bp[dt] + j0);

        int jl = j0 + jg * 8;
        f32x4 ej0 = *reinterpret_cast<const f32x4*>(&e_sl[hq][jl]);
        f32x4 ej1 = *reinterpret_cast<const f32x4*>(&e_sl[hq][jl + 4]);

        short8 af[4];
#pragma unroll
        for (int is = 0; is < 4; ++is) {
            u32 byte = m_lds[is * 16 + row_l][kk] >> (jg * 8);
#pragma unroll
            for (int e = 0; e < 8; ++e) {
                float ejv = (e < 4) ? ej0[e] : ej1[e - 4];
                float wv = ((byte >> e) & 1u) ? fmaxf(Ei[is] * ejv, Ci[is]) : 0.f;
                __hip_bfloat16 bh = __float2bfloat16(wv);
                af[is][e] = (short)*reinterpret_cast<u16*>(&bh);
            }
        }

#pragma unroll
        for (int is = 0; is < 4; ++is) {
#pragma unroll
            for (int dt = 0; dt < 4; ++dt)
                c[is][dt] = __builtin_amdgcn_mfma_f32_16x16x32_bf16(af[is], bf[dt], c[is][dt], 0, 0, 0);
            cl[is] = __builtin_amdgcn_mfma_f32_16x16x32_bf16(af[is], ones, cl[is], 0, 0, 0);
        }
    }

    // write partials. C/D layout: col = lane&15, row = (lane>>4)*4 + reg
    size_t base = ((size_t)(b * 32 + it) * NSL + sl) * CH + hq;
#pragma unroll
    for (int is = 0; is < 4; ++is) {
#pragma unroll
        for (int dt = 0; dt < 4; ++dt)
#pragma unroll
            for (int r = 0; r < 4; ++r)
                partC[(base * ITILE + is * 16 + jg * 4 + r) * CD + dt * 16 + row_l] = c[is][dt][r];
        if (row_l == 0)
#pragma unroll
            for (int r = 0; r < 4; ++r)
                partL[base * ITILE + is * 16 + jg * 4 + r] = cl[is][r];
    }
}

// ---------------------------------------------------------------------------
// Kernel 3: combine slices, divide, mean over heads, leaky relu
// ---------------------------------------------------------------------------
__global__ __launch_bounds__(256) void combine_k(const float* __restrict__ partC,
                                                 const float* __restrict__ partL,
                                                 float* __restrict__ out) {
    int idx = blockIdx.x * 256 + threadIdx.x;   // [b][i][d] flat
    int d = idx & 63;
    int i = (idx >> 6) & 2047;
    int b = idx >> 17;
    int it = i >> 6, row = i & 63;
    float acc = 0.f;
#pragma unroll
    for (int h = 0; h < CH; ++h) {
        float num = 0.f, den = 0.f;
#pragma unroll
        for (int sl = 0; sl < NSL; ++sl) {
            size_t base = ((size_t)(b * 32 + it) * NSL + sl) * CH + h;
            num += partC[(base * ITILE + row) * CD + d];
            den += partL[base * ITILE + row];
        }
        acc += num / fmaxf(den, 1e-30f);
    }
    float o = acc * 0.25f;
    out[idx] = o > 0.f ? o : 0.2f * o;
}

// ---------------------------------------------------------------------------
extern "C" void kernel_launch(void* const* d_in, const int* in_sizes, int n_in,
                              void* d_out, int out_size, void* d_ws, size_t ws_size,
                              hipStream_t stream) {
    const float* X  = (const float*)d_in[0];   // [B,N,F]
    const int*   A  = (const int*)d_in[1];     // [N,N]
    const float* W  = (const float*)d_in[2];   // [H,F,D]
    const float* AK = (const float*)d_in[3];   // [H,D]
    float* out = (float*)d_out;                // [B,N,D]

    char* w = (char*)d_ws;
    float* s_ws = (float*)w;    w += 131072;     // 16*2048 f32
    float* e_ws = (float*)w;    w += 131072;     // 16*2048 f32
    u32* smax_ws = (u32*)w;     w += 256;
    u32* mask_ws = (u32*)w;     w += 524288;     // 2048*64 u32
    u16* hT = (u16*)w;          w += 4194304;    // 16*64*2048 bf16
    float* partL = (float*)w;   w += 524288;     // 4*32*4*4*64 f32
    float* partC = (float*)w;   w += 33554432;   // 4*32*4*4*64*64 f32

    pack_mask_k<<<CN * CN / 256, 256, 0, stream>>>(A, mask_ws, smax_ws);
    proj_k<<<CH * CB * (CN / 32), 256, 0, stream>>>(X, W, AK, hT, s_ws, e_ws, smax_ws);
    attn_k<<<CB * 32 * NSL, 256, 0, stream>>>(hT, s_ws, e_ws, smax_ws, mask_ws, partC, partL);
    combine_k<<<CB * CN * CD / 256, 256, 0, stream>>>(partC, partL, out);
}

// Round 4
// 83.368 us; speedup vs baseline: 3.7481x; 1.2448x over previous
//
#include <hip/hip_runtime.h>
#include <hip/hip_bf16.h>

typedef __attribute__((ext_vector_type(8))) short short8;
typedef __attribute__((ext_vector_type(4))) float f32x4;
typedef unsigned short u16;
typedef unsigned int u32;

constexpr int CB = 4, CN = 2048, CF = 128, CD = 64, CH = 4;
constexpr int ITILE = 64;   // i-rows per attn block (4 MFMA subtiles)
constexpr int NSL = 4;      // k-slices; slice length = 512

__device__ inline u32 fmap(float f) {
    u32 b = __float_as_uint(f);
    return b ^ ((u32)(((int)b) >> 31) | 0x80000000u);
}
__device__ inline float funmap(u32 u) {
    u32 b = (u & 0x80000000u) ? (u ^ 0x80000000u) : ~u;
    return __uint_as_float(b);
}
__device__ inline u16 bf16bits(float v) {
    __hip_bfloat16 b = __float2bfloat16(v);
    return *reinterpret_cast<u16*>(&b);
}

// ---------------------------------------------------------------------------
// Kernel 0: pack adjacency -> bitmask; init smax accumulators.
// ---------------------------------------------------------------------------
__global__ __launch_bounds__(256) void pack_mask_k(const int* __restrict__ A,
                                                   u32* __restrict__ mask,
                                                   u32* __restrict__ smax_u) {
    int gid = blockIdx.x * 256 + threadIdx.x;
    if (blockIdx.x == 0 && threadIdx.x < CH * CB) smax_u[threadIdx.x] = 0u;  // ~ -inf
    unsigned long long mk = __ballot(A[gid] > 0);
    if ((threadIdx.x & 63) == 0) {
        mask[gid >> 5] = (u32)mk;
        mask[(gid >> 5) + 1] = (u32)(mk >> 32);
    }
}

// ---------------------------------------------------------------------------
// Kernel 0b: W [H][F][D] f32 -> WT hi/lo bf16 [H][D][F] (d-major for B-frags)
// ---------------------------------------------------------------------------
__global__ __launch_bounds__(256) void cvt_w_k(const float* __restrict__ W,
                                               u16* __restrict__ WThi,
                                               u16* __restrict__ WTlo) {
    int idx = blockIdx.x * 256 + threadIdx.x;   // H*F*D = 32768
    int h = idx >> 13;
    int f = (idx >> 6) & 127;
    int d = idx & 63;
    float v = W[idx];
    __hip_bfloat16 bh = __float2bfloat16(v);
    float lo = v - __bfloat162float(bh);
    int o = (h * CD + d) * CF + f;
    WThi[o] = *reinterpret_cast<u16*>(&bh);
    WTlo[o] = bf16bits(lo);
}

// ---------------------------------------------------------------------------
// Kernel 1: MFMA projection. wave = (head, 16-row tile); block = 4 waves
// sharing one 16-row X tile. Split-bf16: Xhi*Whi + Xhi*Wlo + Xlo*Whi.
// Emits hT bf16 [h][b][d][j], s f32, E=exp(s) f32, smax atomicMax.
// ---------------------------------------------------------------------------
__global__ __launch_bounds__(256) void proj_k(const float* __restrict__ X,
                                              const u16* __restrict__ WThi,
                                              const u16* __restrict__ WTlo,
                                              const float* __restrict__ AK,
                                              u16* __restrict__ hT,
                                              float* __restrict__ sout,
                                              float* __restrict__ eout,
                                              u32* __restrict__ smax_u) {
    __shared__ float tr[4][CD][17];   // per-wave transpose staging (17.4 KB)

    int blk = blockIdx.x;             // b*128 + ntile
    int ntile = blk & 127;
    int b = blk >> 7;
    int n0 = ntile * 16;
    int t = threadIdx.x;
    int w = t >> 6, l = t & 63;
    int h = w;
    int row_l = l & 15, jg = l >> 4;

    const float* xrow = X + ((size_t)b * CN + n0 + row_l) * CF + jg * 8;
    const u16* whi = WThi + (size_t)h * CD * CF;
    const u16* wlo = WTlo + (size_t)h * CD * CF;

    f32x4 c[4];
    f32x4 zero = {0.f, 0.f, 0.f, 0.f};
#pragma unroll
    for (int dt = 0; dt < 4; ++dt) c[dt] = zero;

#pragma unroll
    for (int kk = 0; kk < 4; ++kk) {
        float4 xa = *reinterpret_cast<const float4*>(xrow + kk * 32);
        float4 xb = *reinterpret_cast<const float4*>(xrow + kk * 32 + 4);
        float xv[8] = {xa.x, xa.y, xa.z, xa.w, xb.x, xb.y, xb.z, xb.w};
        short8 ahi, alo;
#pragma unroll
        for (int e = 0; e < 8; ++e) {
            __hip_bfloat16 bh = __float2bfloat16(xv[e]);
            ahi[e] = (short)*reinterpret_cast<u16*>(&bh);
            alo[e] = (short)bf16bits(xv[e] - __bfloat162float(bh));
        }
#pragma unroll
        for (int dt = 0; dt < 4; ++dt) {
            const u16* wp = whi + (dt * 16 + row_l) * CF + kk * 32 + jg * 8;
            const u16* wq = wlo + (dt * 16 + row_l) * CF + kk * 32 + jg * 8;
            short8 bhi = *reinterpret_cast<const short8*>(wp);
            short8 blo = *reinterpret_cast<const short8*>(wq);
            c[dt] = __builtin_amdgcn_mfma_f32_16x16x32_bf16(ahi, bhi, c[dt], 0, 0, 0);
            c[dt] = __builtin_amdgcn_mfma_f32_16x16x32_bf16(ahi, blo, c[dt], 0, 0, 0);
            c[dt] = __builtin_amdgcn_mfma_f32_16x16x32_bf16(alo, bhi, c[dt], 0, 0, 0);
        }
    }

    // ---- s = h . a, shuffle-reduced over the 16 d-cols each lane owns ----
    float av[4];
#pragma unroll
    for (int dt = 0; dt < 4; ++dt) av[dt] = AK[h * CD + dt * 16 + row_l];
    float sacc[4];
#pragma unroll
    for (int r = 0; r < 4; ++r)
        sacc[r] = c[0][r] * av[0] + c[1][r] * av[1] + c[2][r] * av[2] + c[3][r] * av[3];
#pragma unroll
    for (int off = 1; off <= 8; off <<= 1)
#pragma unroll
        for (int r = 0; r < 4; ++r) sacc[r] += __shfl_xor(sacc[r], off, 64);
    // all lanes now hold s for rows n0 + jg*4 + r

    float mx = fmaxf(fmaxf(sacc[0], sacc[1]), fmaxf(sacc[2], sacc[3]));
    mx = fmaxf(mx, __shfl_xor(mx, 16, 64));
    mx = fmaxf(mx, __shfl_xor(mx, 32, 64));
    if (l == 0) atomicMax(&smax_u[h * CB + b], fmap(mx));

    if (row_l == 0) {
#pragma unroll
        for (int r = 0; r < 4; ++r) {
            size_t si = (size_t)(h * CB + b) * CN + n0 + jg * 4 + r;
            sout[si] = sacc[r];
            eout[si] = __expf(sacc[r]);
        }
    }

    // ---- transpose h to d-major bf16 hT via LDS ----
#pragma unroll
    for (int dt = 0; dt < 4; ++dt)
#pragma unroll
        for (int r = 0; r < 4; ++r) tr[w][dt * 16 + row_l][jg * 4 + r] = c[dt][r];
    __syncthreads();

#pragma unroll
    for (int ch = 0; ch < 2; ++ch) {
        short8 pk;
#pragma unroll
        for (int e = 0; e < 8; ++e) pk[e] = (short)bf16bits(tr[w][l][ch * 8 + e]);
        *reinterpret_cast<short8*>(hT + ((size_t)((h * CB + b) * CD + l)) * CN + n0 + ch * 8) = pk;
    }
}

// ---------------------------------------------------------------------------
// Kernel 2: MFMA flash PV. block = (b, 64-row i-tile, k-slice of 512),
// grid = 4*32*4 = 512, 256 threads = 4 waves (wave = head).
// Weight w = mask ? max(Ei*Ej, Ci) : 0   (no transcendentals in loop).
// Denominator = ones-column MFMA of the SAME bf16-rounded A-frag.
// ---------------------------------------------------------------------------
__global__ __launch_bounds__(256, 2) void attn_k(const u16* __restrict__ hT,
                                                 const float* __restrict__ s_ws,
                                                 const float* __restrict__ e_ws,
                                                 const u32* __restrict__ smax_u,
                                                 const u32* __restrict__ mask32,
                                                 float* __restrict__ partC,
                                                 float* __restrict__ partL) {
    __shared__ alignas(16) float e_sl[CH][512];  // 8 KB: E_j slice, 4 heads
    __shared__ u32 m_lds[ITILE][17];             // 4.4 KB mask words (pad)

    int blk = blockIdx.x;
    int sl = blk & 3;
    int it = (blk >> 2) & 31;
    int b = blk >> 7;
    int t = threadIdx.x, l = t & 63, hq = t >> 6;
    int j_base = sl * 512;

    for (int idx = t; idx < CH * 512; idx += 256) {
        int hh = idx >> 9, j = idx & 511;
        e_sl[hh][j] = e_ws[(size_t)(hh * CB + b) * CN + j_base + j];
    }
    for (int idx = t; idx < ITILE * 16; idx += 256) {
        int r = idx >> 4, w = idx & 15;
        m_lds[r][w] = mask32[(size_t)(it * ITILE + r) * 64 + sl * 16 + w];
    }
    __syncthreads();

    int row_l = l & 15;   // A row / D col within 16
    int jg = l >> 4;      // k-group
    float smax = funmap(smax_u[hq * CB + b]);

    float Ei[4], Ci[4];
#pragma unroll
    for (int is = 0; is < 4; ++is) {
        float si = s_ws[(size_t)(hq * CB + b) * CN + it * ITILE + is * 16 + row_l];
        float m = fmaxf(si + smax, 0.f);
        Ei[is] = __expf(si - m);
        Ci[is] = __expf(-m);
    }

    f32x4 c[4][4], cl[4];
    f32x4 zero = {0.f, 0.f, 0.f, 0.f};
#pragma unroll
    for (int is = 0; is < 4; ++is) {
        cl[is] = zero;
#pragma unroll
        for (int dt = 0; dt < 4; ++dt) c[is][dt] = zero;
    }

    short8 ones;
#pragma unroll
    for (int e = 0; e < 8; ++e) ones[e] = (short)0x3F80;  // bf16 1.0

    const u16* bp[4];
#pragma unroll
    for (int dt = 0; dt < 4; ++dt)
        bp[dt] = hT + ((size_t)((hq * CB + b) * CD + dt * 16 + row_l)) * CN + j_base + jg * 8;

#pragma unroll 2
    for (int kk = 0; kk < 16; ++kk) {
        int j0 = kk * 32;
        short8 bf[4];
#pragma unroll
        for (int dt = 0; dt < 4; ++dt)
            bf[dt] = *reinterpret_cast<const short8*>(bp[dt] + j0);

        int jl = j0 + jg * 8;
        f32x4 ej0 = *reinterpret_cast<const f32x4*>(&e_sl[hq][jl]);
        f32x4 ej1 = *reinterpret_cast<const f32x4*>(&e_sl[hq][jl + 4]);

        short8 af[4];
#pragma unroll
        for (int is = 0; is < 4; ++is) {
            u32 byte = m_lds[is * 16 + row_l][kk] >> (jg * 8);
#pragma unroll
            for (int e = 0; e < 8; ++e) {
                float ejv = (e < 4) ? ej0[e] : ej1[e - 4];
                float wv = ((byte >> e) & 1u) ? fmaxf(Ei[is] * ejv, Ci[is]) : 0.f;
                af[is][e] = (short)bf16bits(wv);
            }
        }

#pragma unroll
        for (int is = 0; is < 4; ++is) {
#pragma unroll
            for (int dt = 0; dt < 4; ++dt)
                c[is][dt] = __builtin_amdgcn_mfma_f32_16x16x32_bf16(af[is], bf[dt], c[is][dt], 0, 0, 0);
            cl[is] = __builtin_amdgcn_mfma_f32_16x16x32_bf16(af[is], ones, cl[is], 0, 0, 0);
        }
    }

    // write partials. C/D layout: col = lane&15, row = (lane>>4)*4 + reg
    size_t base = ((size_t)(b * 32 + it) * NSL + sl) * CH + hq;
#pragma unroll
    for (int is = 0; is < 4; ++is) {
#pragma unroll
        for (int dt = 0; dt < 4; ++dt)
#pragma unroll
            for (int r = 0; r < 4; ++r)
                partC[(base * ITILE + is * 16 + jg * 4 + r) * CD + dt * 16 + row_l] = c[is][dt][r];
        if (row_l == 0)
#pragma unroll
            for (int r = 0; r < 4; ++r)
                partL[base * ITILE + is * 16 + jg * 4 + r] = cl[is][r];
    }
}

// ---------------------------------------------------------------------------
// Kernel 3: combine slices, divide, mean over heads, leaky relu
// ---------------------------------------------------------------------------
__global__ __launch_bounds__(256) void combine_k(const float* __restrict__ partC,
                                                 const float* __restrict__ partL,
                                                 float* __restrict__ out) {
    int idx = blockIdx.x * 256 + threadIdx.x;   // [b][i][d] flat
    int d = idx & 63;
    int i = (idx >> 6) & 2047;
    int b = idx >> 17;
    int it = i >> 6, row = i & 63;
    float acc = 0.f;
#pragma unroll
    for (int h = 0; h < CH; ++h) {
        float num = 0.f, den = 0.f;
#pragma unroll
        for (int sl = 0; sl < NSL; ++sl) {
            size_t base = ((size_t)(b * 32 + it) * NSL + sl) * CH + h;
            num += partC[(base * ITILE + row) * CD + d];
            den += partL[base * ITILE + row];
        }
        acc += num / fmaxf(den, 1e-30f);
    }
    float o = acc * 0.25f;
    out[idx] = o > 0.f ? o : 0.2f * o;
}

// ---------------------------------------------------------------------------
extern "C" void kernel_launch(void* const* d_in, const int* in_sizes, int n_in,
                              void* d_out, int out_size, void* d_ws, size_t ws_size,
                              hipStream_t stream) {
    const float* X  = (const float*)d_in[0];   // [B,N,F]
    const int*   A  = (const int*)d_in[1];     // [N,N]
    const float* W  = (const float*)d_in[2];   // [H,F,D]
    const float* AK = (const float*)d_in[3];   // [H,D]
    float* out = (float*)d_out;                // [B,N,D]

    char* w = (char*)d_ws;
    float* s_ws = (float*)w;    w += 131072;     // 16*2048 f32
    float* e_ws = (float*)w;    w += 131072;     // 16*2048 f32
    u32* smax_ws = (u32*)w;     w += 256;
    u32* mask_ws = (u32*)w;     w += 524288;     // 2048*64 u32
    u16* hT = (u16*)w;          w += 4194304;    // 16*64*2048 bf16
    u16* WThi = (u16*)w;        w += 65536;      // 4*64*128 bf16
    u16* WTlo = (u16*)w;        w += 65536;
    float* partL = (float*)w;   w += 524288;     // 4*32*4*4*64 f32
    float* partC = (float*)w;   w += 33554432;   // 4*32*4*4*64*64 f32

    pack_mask_k<<<CN * CN / 256, 256, 0, stream>>>(A, mask_ws, smax_ws);
    cvt_w_k<<<CH * CF * CD / 256, 256, 0, stream>>>(W, WThi, WTlo);
    proj_k<<<CB * (CN / 16), 256, 0, stream>>>(X, WThi, WTlo, AK, hT, s_ws, e_ws, smax_ws);
    attn_k<<<CB * 32 * NSL, 256, 0, stream>>>(hT, s_ws, e_ws, smax_ws, mask_ws, partC, partL);
    combine_k<<<CB * CN * CD / 256, 256, 0, stream>>>(partC, partL, out);
}